// Round 14
// baseline (845.844 us; speedup 1.0000x reference)
//
#include <hip/hip_runtime.h>
#include <hip/hip_bf16.h>
#include <hip/hip_fp16.h>

#define NLAYERS 4
#define GRID_STRIDE 2048

typedef _Float16 half8_t __attribute__((ext_vector_type(8)));
typedef float float4_t __attribute__((ext_vector_type(4)));

// ---------------- small zero kernel ----------------
__global__ void zero_ints(int* __restrict__ p, int n)
{
    int i = blockIdx.x * 256 + threadIdx.x;
    if (i < n) p[i] = 0;
}

// ---------------- CSR build ----------------
__global__ void hist_kernel(const int* __restrict__ dsts, int* __restrict__ counts, int E)
{
    int i = blockIdx.x * 256 + threadIdx.x;
    if (i < E) atomicAdd(&counts[dsts[i]], 1);
}

__global__ __launch_bounds__(256) void scan1(const int* __restrict__ counts,
                                             int* __restrict__ offsets,
                                             int* __restrict__ blocksums, int N)
{
    __shared__ int sdata[256];
    int t = threadIdx.x;
    int bbase = blockIdx.x * 1024;
    int v[4]; int s = 0;
#pragma unroll
    for (int q = 0; q < 4; q++) {
        int idx = bbase + t * 4 + q;
        v[q] = (idx < N) ? counts[idx] : 0;
        s += v[q];
    }
    sdata[t] = s;
    __syncthreads();
    for (int off = 1; off < 256; off <<= 1) {
        int x = (t >= off) ? sdata[t - off] : 0;
        __syncthreads();
        sdata[t] += x;
        __syncthreads();
    }
    int excl = sdata[t] - s;
    int run = excl;
#pragma unroll
    for (int q = 0; q < 4; q++) {
        int idx = bbase + t * 4 + q;
        if (idx < N) offsets[idx] = run;
        run += v[q];
    }
    if (t == 255) blocksums[blockIdx.x] = sdata[255];
}

__global__ void scan2(int* __restrict__ blocksums, int nb)
{
    if (threadIdx.x == 0 && blockIdx.x == 0) {
        int run = 0;
        for (int b = 0; b < nb; b++) { int t = blocksums[b]; blocksums[b] = run; run += t; }
    }
}

__global__ void scan3(int* __restrict__ offsets, const int* __restrict__ blocksums,
                      int* __restrict__ cursor, int N)
{
    int i = blockIdx.x * 256 + threadIdx.x;
    if (i < N) {
        int v = offsets[i] + blocksums[i >> 10];
        offsets[i] = v;
        cursor[i] = v;
    }
}

// scatter only perm (1 random 4B stream instead of 3)
__global__ void scatter_perm(const int* __restrict__ dsts, int* __restrict__ cursor,
                             int* __restrict__ perm, int E)
{
    int i = blockIdx.x * 256 + threadIdx.x;
    if (i < E) {
        int slot = atomicAdd(&cursor[dsts[i]], 1);
        perm[slot] = i;
    }
}

// coalesced writes, cache-resident random reads
__global__ void gather_sd(const int* __restrict__ perm, const int* __restrict__ srcs,
                          const int* __restrict__ dsts, int* __restrict__ srcp,
                          int* __restrict__ dstp, int E)
{
    int i = blockIdx.x * 256 + threadIdx.x;
    if (i < E) {
        int e = perm[i];
        srcp[i] = srcs[e];
        dstp[i] = dsts[e];
    }
}

// ---------------- init projections ----------------
__global__ void init_proj4(const float* __restrict__ in, const float* __restrict__ w,
                           const float* __restrict__ b, float4* __restrict__ out, size_t n4)
{
    size_t i = (size_t)blockIdx.x * 256 + threadIdx.x;
    if (i < n4) {
        int j4 = (int)(i & 7) * 4;
        float xv = in[i >> 3];
        float4 wv = *(const float4*)(w + j4);
        float4 bv = *(const float4*)(b + j4);
        out[i] = make_float4(fmaf(xv, wv.x, bv.x), fmaf(xv, wv.y, bv.y),
                             fmaf(xv, wv.z, bv.z), fmaf(xv, wv.w, bv.w));
    }
}

__global__ void init_ep16(const float* __restrict__ e_in, const int* __restrict__ perm,
                          const float* __restrict__ w, const float* __restrict__ b,
                          __half2* __restrict__ out, size_t n4)
{
    size_t i = (size_t)blockIdx.x * 256 + threadIdx.x;
    if (i < n4) {
        int row = (int)(i >> 3);
        float xv = e_in[perm[row]];
        int j4 = (int)(i & 7) * 4;
        float4 wv = *(const float4*)(w + j4);
        float4 bv = *(const float4*)(b + j4);
        out[i * 2]     = __floats2half2_rn(fmaf(xv, wv.x, bv.x), fmaf(xv, wv.y, bv.y));
        out[i * 2 + 1] = __floats2half2_rn(fmaf(xv, wv.z, bv.z), fmaf(xv, wv.w, bv.w));
    }
}

// ---------------- node GEMMs: one node per thread, scalar-broadcast weights ----------------
__device__ __forceinline__ void mat32(const float* __restrict__ hrow,
                                      const float* __restrict__ W, const float* __restrict__ Wb,
                                      float* __restrict__ dst)
{
    float acc[32];
#pragma unroll
    for (int j = 0; j < 32; j++) acc[j] = Wb[j];
#pragma unroll 4
    for (int k = 0; k < 32; k++) {
        float hk = hrow[k];
#pragma unroll
        for (int j = 0; j < 32; j++) acc[j] = fmaf(hk, W[k * 32 + j], acc[j]);
    }
    float4* o = (float4*)dst;
#pragma unroll
    for (int q = 0; q < 8; q++) o[q] = make_float4(acc[4*q], acc[4*q+1], acc[4*q+2], acc[4*q+3]);
}

__device__ __forceinline__ void mat32h(const float* __restrict__ hrow,
                                       const float* __restrict__ W, const float* __restrict__ Wb,
                                       __half* __restrict__ dst)
{
    float acc[32];
#pragma unroll
    for (int j = 0; j < 32; j++) acc[j] = Wb[j];
#pragma unroll 4
    for (int k = 0; k < 32; k++) {
        float hk = hrow[k];
#pragma unroll
        for (int j = 0; j < 32; j++) acc[j] = fmaf(hk, W[k * 32 + j], acc[j]);
    }
    __half2* o = (__half2*)dst;
#pragma unroll
    for (int q = 0; q < 16; q++) o[q] = __floats2half2_rn(acc[2*q], acc[2*q+1]);
}

__global__ __launch_bounds__(64) void node_gemm(
    const float* __restrict__ h,
    const float* __restrict__ Aw, const float* __restrict__ Ab,
    const float* __restrict__ Bw, const float* __restrict__ Bb,
    const float* __restrict__ Uw, const float* __restrict__ Ub,
    const float* __restrict__ Vw, const float* __restrict__ Vb,
    __half* __restrict__ Ahh, __half* __restrict__ Bhh,
    float* __restrict__ Uhh, __half* __restrict__ Vhh, int N)
{
    int nid = blockIdx.x * 64 + threadIdx.x;
    if (nid >= N) return;
    const float* hrow = h + (size_t)nid * 32;
    size_t o = (size_t)nid * 32;
    mat32h(hrow, Aw, Ab, Ahh + o);
    mat32h(hrow, Bw, Bb, Bhh + o);
    mat32(hrow, Uw, Ub, Uhh + o);   // Uhh == hnew (folded)
    mat32h(hrow, Vw, Vb, Vhh + o);
}

// ---- phase A (MFMA): en = e @ Cw + Cb + Ah[dst] + Bh[src] for 16-edge tiles per wave ----
// FUSE: during A-frag load, applies prev layer's e-update: ep += relu(enh_prev*sc+sh).
// Safe: each 16-row tile is touched by exactly one wave; read->MFMA->write dependency
// orders the in-tile RMW.
template <int FUSE>
__global__ __launch_bounds__(256) void edge_en(
    __half* __restrict__ ep,
    const float* __restrict__ sc_e, const float* __restrict__ sh_e,
    const int* __restrict__ srcp, const int* __restrict__ dstp,
    const __half* __restrict__ Ah, const __half* __restrict__ Bh,
    const float* __restrict__ Cw, const float* __restrict__ Cb,
    __half* __restrict__ enh, float* __restrict__ partial, int E)
{
    __shared__ float red[256];
    int tid = threadIdx.x;
    int lane = tid & 63;
    int m = lane & 15, q = lane >> 4;         // q in 0..3
    half8_t b0, b1;
    float sc8[8], sh8[8];
#pragma unroll
    for (int i = 0; i < 8; i++) {
        int k = q * 8 + i;
        b0[i] = (_Float16)Cw[k * 32 + m];
        b1[i] = (_Float16)Cw[k * 32 + m + 16];
        if (FUSE) { sc8[i] = sc_e[k]; sh8[i] = sh_e[k]; }
    }
    float cb0 = Cb[m], cb1 = Cb[m + 16];
    float es0 = 0.f, eq0 = 0.f, es1 = 0.f, eq1 = 0.f;

    int ntile = (E + 15) >> 4;
    int wid = blockIdx.x * 4 + (tid >> 6);
    int nwave = gridDim.x * 4;
    for (int t = wid; t < ntile; t += nwave) {
        int base = t << 4;
        int arow = base + m;
        bool valid = arow < E;
        if (!valid) arow = E - 1;
        half8_t a;
        if (FUSE) {
            half8_t epv = *(const half8_t*)(ep + (size_t)arow * 32 + q * 8);
            half8_t env = *(const half8_t*)(enh + (size_t)arow * 32 + q * 8);
#pragma unroll
            for (int i = 0; i < 8; i++) {
                float e = (float)epv[i] + fmaxf(fmaf((float)env[i], sc8[i], sh8[i]), 0.f);
                a[i] = (_Float16)e;
            }
            if (valid) *(half8_t*)(ep + (size_t)arow * 32 + q * 8) = a;
        } else {
            a = *(const half8_t*)(ep + (size_t)arow * 32 + q * 8);
        }
        float4_t acc0 = __builtin_amdgcn_mfma_f32_16x16x32_f16(a, b0, (float4_t){0.f,0.f,0.f,0.f}, 0, 0, 0);
        float4_t acc1 = __builtin_amdgcn_mfma_f32_16x16x32_f16(a, b1, (float4_t){0.f,0.f,0.f,0.f}, 0, 0, 0);
#pragma unroll
        for (int reg = 0; reg < 4; reg++) {
            int row = q * 4 + reg;
            int edge = base + row;
            if (edge < E) {
                int s = srcp[edge], d = dstp[edge];
                float ah0 = __half2float(Ah[(size_t)d * 32 + m]);
                float bh0 = __half2float(Bh[(size_t)s * 32 + m]);
                float ah1 = __half2float(Ah[(size_t)d * 32 + m + 16]);
                float bh1 = __half2float(Bh[(size_t)s * 32 + m + 16]);
                float en0 = acc0[reg] + cb0 + ah0 + bh0;
                float en1 = acc1[reg] + cb1 + ah1 + bh1;
                enh[(size_t)edge * 32 + m]      = __float2half_rn(en0);
                enh[(size_t)edge * 32 + m + 16] = __float2half_rn(en1);
                es0 += en0; eq0 += en0 * en0;
                es1 += en1; eq1 += en1 * en1;
            }
        }
    }
    float* p = partial + (size_t)blockIdx.x * 64;
    __syncthreads();
    red[tid] = es0;
    __syncthreads();
    if (tid < 16) {
        float s = 0.f;
#pragma unroll
        for (int w = 0; w < 4; w++)
#pragma unroll
            for (int k = 0; k < 4; k++) s += red[w * 64 + k * 16 + tid];
        p[tid] = s;
    }
    __syncthreads();
    red[tid] = es1;
    __syncthreads();
    if (tid < 16) {
        float s = 0.f;
#pragma unroll
        for (int w = 0; w < 4; w++)
#pragma unroll
            for (int k = 0; k < 4; k++) s += red[w * 64 + k * 16 + tid];
        p[16 + tid] = s;
    }
    __syncthreads();
    red[tid] = eq0;
    __syncthreads();
    if (tid < 16) {
        float s = 0.f;
#pragma unroll
        for (int w = 0; w < 4; w++)
#pragma unroll
            for (int k = 0; k < 4; k++) s += red[w * 64 + k * 16 + tid];
        p[32 + tid] = s;
    }
    __syncthreads();
    red[tid] = eq1;
    __syncthreads();
    if (tid < 16) {
        float s = 0.f;
#pragma unroll
        for (int w = 0; w < 4; w++)
#pragma unroll
            for (int k = 0; k < 4; k++) s += red[w * 64 + k * 16 + tid];
        p[48 + tid] = s;
    }
}

// ---- phase B: CSR walk; sigmoid + Vh gather; register num/den; h-BN partials ----
__global__ __launch_bounds__(256) void node_agg(
    const __half* __restrict__ enh, const int* __restrict__ srcp,
    const int* __restrict__ offsets, const int* __restrict__ counts,
    const __half* __restrict__ Vh, float* __restrict__ hnew,
    float* __restrict__ partial, int N)
{
    __shared__ float red[256];
    int tid = threadIdx.x, j = tid & 31, grp = tid >> 5;
    float hsum = 0.f, hsq = 0.f;
    for (int nb0 = blockIdx.x * 8; nb0 < N; nb0 += gridDim.x * 8) {
        int node = nb0 + grp;
        if (node >= N) break;
        int start = offsets[node], len = counts[node];
        float num = 0.f, den = 0.f;
        int qq = 0;
        for (; qq + 2 <= len; qq += 2) {
            int p0 = start + qq, p1 = p0 + 1;
            int s0 = srcp[p0], s1 = srcp[p1];
            float en0 = __half2float(enh[(size_t)p0 * 32 + j]);
            float en1 = __half2float(enh[(size_t)p1 * 32 + j]);
            float vh0 = __half2float(Vh[(size_t)s0 * 32 + j]);
            float vh1 = __half2float(Vh[(size_t)s1 * 32 + j]);
            float sg0 = 1.f / (1.f + __expf(-en0));
            float sg1 = 1.f / (1.f + __expf(-en1));
            num = fmaf(sg0, vh0, num); num = fmaf(sg1, vh1, num);
            den += sg0 + sg1;
        }
        if (qq < len) {
            int p0 = start + qq;
            int s0 = srcp[p0];
            float en0 = __half2float(enh[(size_t)p0 * 32 + j]);
            float vh0 = __half2float(Vh[(size_t)s0 * 32 + j]);
            float sg0 = 1.f / (1.f + __expf(-en0));
            num = fmaf(sg0, vh0, num);
            den += sg0;
        }
        size_t ho = (size_t)node * 32 + j;
        float hv = hnew[ho] + num / (den + 1e-6f);   // hnew holds Uh
        hnew[ho] = hv;
        hsum += hv; hsq += hv * hv;
    }
    __syncthreads();
    red[tid] = hsum;
    __syncthreads();
    float hS = 0.f;
    if (tid < 32) {
#pragma unroll
        for (int r = 0; r < 8; r++) hS += red[r * 32 + tid];
    }
    __syncthreads();
    red[tid] = hsq;
    __syncthreads();
    if (tid < 32) {
        float hQ = 0.f;
#pragma unroll
        for (int r = 0; r < 8; r++) hQ += red[r * 32 + tid];
        float* p = partial + (size_t)blockIdx.x * 64;
        p[tid] = hS; p[32 + tid] = hQ;
    }
}

// ---------------- finalize BN stats for one side: 32 blocks, one per feature ----------------
__global__ __launch_bounds__(256) void stats_side(
    const float* __restrict__ partial, int nrows, double cnt,
    const float* __restrict__ g, const float* __restrict__ b,
    float* __restrict__ sc_out, float* __restrict__ sh_out)
{
    int j = blockIdx.x;
    __shared__ double rs[256], rq[256];
    double s = 0.0, q = 0.0;
    for (int r = threadIdx.x; r < nrows; r += 256) {
        s += (double)partial[(size_t)r * 64 + j];
        q += (double)partial[(size_t)r * 64 + 32 + j];
    }
    rs[threadIdx.x] = s; rq[threadIdx.x] = q;
    __syncthreads();
    for (int off = 128; off; off >>= 1) {
        if (threadIdx.x < off) { rs[threadIdx.x] += rs[threadIdx.x + off]; rq[threadIdx.x] += rq[threadIdx.x + off]; }
        __syncthreads();
    }
    if (threadIdx.x == 0) {
        double mean = rs[0] / cnt;
        double var = rq[0] / cnt - mean * mean;
        float scale = g[j] * (float)(1.0 / sqrt(var + 1e-5));
        sc_out[j] = scale;
        sh_out[j] = b[j] - (float)mean * scale;
    }
}

// ---------------- apply (float4): acc += relu(pre*scale + shift) ----------------
__global__ void apply4(const float4* __restrict__ pre, const float* __restrict__ scale,
                       const float* __restrict__ shift, float4* __restrict__ acc, size_t n4)
{
    size_t i = (size_t)blockIdx.x * 256 + threadIdx.x;
    if (i < n4) {
        int j4 = (int)(i & 7) * 4;
        float4 sc = *(const float4*)(scale + j4);
        float4 sh = *(const float4*)(shift + j4);
        float4 p = pre[i], a = acc[i];
        a.x += fmaxf(fmaf(p.x, sc.x, sh.x), 0.f);
        a.y += fmaxf(fmaf(p.y, sc.y, sh.y), 0.f);
        a.z += fmaxf(fmaf(p.z, sc.z, sh.z), 0.f);
        a.w += fmaxf(fmaf(p.w, sc.w, sh.w), 0.f);
        acc[i] = a;
    }
}

// ---- final h apply: h16 = fp16(h + relu(hnew*sc+sh)) into a separate buffer ----
__global__ void apply4_h16(const float4* __restrict__ pre, const float* __restrict__ scale,
                           const float* __restrict__ shift, const float4* __restrict__ hold,
                           __half2* __restrict__ h16, size_t n4)
{
    size_t i = (size_t)blockIdx.x * 256 + threadIdx.x;
    if (i < n4) {
        int j4 = (int)(i & 7) * 4;
        float4 sc = *(const float4*)(scale + j4);
        float4 sh = *(const float4*)(shift + j4);
        float4 p = pre[i], a = hold[i];
        a.x += fmaxf(fmaf(p.x, sc.x, sh.x), 0.f);
        a.y += fmaxf(fmaf(p.y, sc.y, sh.y), 0.f);
        a.z += fmaxf(fmaf(p.z, sc.z, sh.z), 0.f);
        a.w += fmaxf(fmaf(p.w, sc.w, sh.w), 0.f);
        h16[i * 2]     = __floats2half2_rn(a.x, a.y);
        h16[i * 2 + 1] = __floats2half2_rn(a.z, a.w);
    }
}

// ---- predictor (MFMA): applies final e-update on the fly; [16×96]@[96×32] + W2 epilogue ----
__global__ __launch_bounds__(256) void predictor(
    const __half* __restrict__ h16, const __half* __restrict__ ep,
    const __half* __restrict__ enh,
    const float* __restrict__ sc_e, const float* __restrict__ sh_e,
    const int* __restrict__ srcp, const int* __restrict__ dstp, const int* __restrict__ perm,
    const float* __restrict__ W1, const float* __restrict__ b1,
    const float* __restrict__ W2, const float* __restrict__ b2v,
    float* __restrict__ out, int E)
{
    int tid = threadIdx.x;
    int lane = tid & 63;
    int m = lane & 15, q = lane >> 4;
    half8_t bf00, bf01, bf10, bf11, bf20, bf21;
    float sc8[8], sh8[8];
#pragma unroll
    for (int i = 0; i < 8; i++) {
        int k = q * 8 + i;
        bf00[i] = (_Float16)W1[k * 32 + m];
        bf01[i] = (_Float16)W1[k * 32 + m + 16];
        bf10[i] = (_Float16)W1[(32 + k) * 32 + m];
        bf11[i] = (_Float16)W1[(32 + k) * 32 + m + 16];
        bf20[i] = (_Float16)W1[(64 + k) * 32 + m];
        bf21[i] = (_Float16)W1[(64 + k) * 32 + m + 16];
        sc8[i] = sc_e[k]; sh8[i] = sh_e[k];
    }
    float b10 = b1[m], b11 = b1[m + 16];
    float w20 = W2[m], w21 = W2[m + 16];
    float b2 = b2v[0];

    int ntile = (E + 15) >> 4;
    int wid = blockIdx.x * 4 + (tid >> 6);
    int nwave = gridDim.x * 4;
    for (int t = wid; t < ntile; t += nwave) {
        int base = t << 4;
        int arow = base + m;
        if (arow >= E) arow = E - 1;
        int s = srcp[arow], d = dstp[arow];
        half8_t a0 = *(const half8_t*)(h16 + (size_t)s * 32 + q * 8);
        half8_t a1 = *(const half8_t*)(h16 + (size_t)d * 32 + q * 8);
        half8_t epv = *(const half8_t*)(ep + (size_t)arow * 32 + q * 8);
        half8_t env = *(const half8_t*)(enh + (size_t)arow * 32 + q * 8);
        half8_t a2;
#pragma unroll
        for (int i = 0; i < 8; i++) {
            float e = (float)epv[i] + fmaxf(fmaf((float)env[i], sc8[i], sh8[i]), 0.f);
            a2[i] = (_Float16)e;
        }
        float4_t acc0 = {0.f, 0.f, 0.f, 0.f}, acc1 = {0.f, 0.f, 0.f, 0.f};
        acc0 = __builtin_amdgcn_mfma_f32_16x16x32_f16(a0, bf00, acc0, 0, 0, 0);
        acc1 = __builtin_amdgcn_mfma_f32_16x16x32_f16(a0, bf01, acc1, 0, 0, 0);
        acc0 = __builtin_amdgcn_mfma_f32_16x16x32_f16(a1, bf10, acc0, 0, 0, 0);
        acc1 = __builtin_amdgcn_mfma_f32_16x16x32_f16(a1, bf11, acc1, 0, 0, 0);
        acc0 = __builtin_amdgcn_mfma_f32_16x16x32_f16(a2, bf20, acc0, 0, 0, 0);
        acc1 = __builtin_amdgcn_mfma_f32_16x16x32_f16(a2, bf21, acc1, 0, 0, 0);
#pragma unroll
        for (int reg = 0; reg < 4; reg++) {
            float tp = fmaxf(acc0[reg] + b10, 0.f) * w20
                     + fmaxf(acc1[reg] + b11, 0.f) * w21;
            tp += __shfl_xor(tp, 1);
            tp += __shfl_xor(tp, 2);
            tp += __shfl_xor(tp, 4);
            tp += __shfl_xor(tp, 8);
            int edge = base + q * 4 + reg;
            if (m == 0 && edge < E) out[perm[edge]] = tp + b2;
        }
    }
}

extern "C" void kernel_launch(void* const* d_in, const int* in_sizes, int n_in,
                              void* d_out, int out_size, void* d_ws, size_t ws_size,
                              hipStream_t stream)
{
    const int N = in_sizes[0];
    const int E = in_sizes[1];

    const float* x    = (const float*)d_in[0];
    const float* e_in = (const float*)d_in[1];
    const int*   eidx = (const int*)d_in[2];
    const float* pe_w = (const float*)d_in[3];
    const float* pe_b = (const float*)d_in[4];
    const float* ed_w = (const float*)d_in[5];
    const float* ed_b = (const float*)d_in[6];
    const float* Aw = (const float*)d_in[7];
    const float* Ab = (const float*)d_in[8];
    const float* Bw = (const float*)d_in[9];
    const float* Bb = (const float*)d_in[10];
    const float* Cw = (const float*)d_in[11];
    const float* Cb = (const float*)d_in[12];
    const float* Uw = (const float*)d_in[13];
    const float* Ub = (const float*)d_in[14];
    const float* Vw = (const float*)d_in[15];
    const float* Vb = (const float*)d_in[16];
    const float* bn_h_g = (const float*)d_in[17];
    const float* bn_h_b = (const float*)d_in[18];
    const float* bn_e_g = (const float*)d_in[19];
    const float* bn_e_b = (const float*)d_in[20];
    const float* W1w = (const float*)d_in[21];
    const float* W1b = (const float*)d_in[22];
    const float* W2w = (const float*)d_in[23];
    const float* W2b = (const float*)d_in[24];

    const int* srcs = eidx;
    const int* dsts = eidx + E;

    size_t nh = (size_t)N * 32;
    size_t eh = (size_t)E * 32;

    float* ws = (float*)d_ws;
    float* stats     = ws;                            // 128
    float* partial_h = stats + 128;                   // GRID_STRIDE*64
    float* partial_e = partial_h + GRID_STRIDE * 64;  // GRID_STRIDE*64
    float* h    = partial_e + GRID_STRIDE * 64;       // nh floats
    float* hnew = h + nh;                             // nh floats (Uh then h_new)
    __half* Ah  = (__half*)(hnew + nh);               // nh halves (h16 at the end)
    __half* Bh  = Ah + nh;                            // nh halves
    __half* Vh  = Bh + nh;                            // nh halves
    __half* ep  = Vh + nh;                            // eh halves
    __half* enh = ep + eh;                            // eh halves
    int* counts    = (int*)(enh + eh);
    int* offsets   = counts + N;
    int* cursor    = offsets + N;
    int* blocksums = cursor + N;   // 128
    int* perm      = blocksums + 128;
    int* srcp      = perm + E;
    int* dstp      = srcp + E;

    size_t nh4 = nh / 4, eh4 = eh / 4;
    int gh4 = (int)((nh4 + 255) / 256);
    int ge4 = (int)((eh4 + 255) / 256);
    int gN = (N + 255) / 256;
    int gE = (E + 255) / 256;
    int nb = (N + 1023) / 1024;

    // ---- CSR build (dst-sorted edge permutation) ----
    zero_ints<<<gN, 256, 0, stream>>>(counts, N);
    hist_kernel<<<gE, 256, 0, stream>>>(dsts, counts, E);
    scan1<<<nb, 256, 0, stream>>>(counts, offsets, blocksums, N);
    scan2<<<1, 64, 0, stream>>>(blocksums, nb);
    scan3<<<gN, 256, 0, stream>>>(offsets, blocksums, cursor, N);
    scatter_perm<<<gE, 256, 0, stream>>>(dsts, cursor, perm, E);
    gather_sd<<<gE, 256, 0, stream>>>(perm, srcs, dsts, srcp, dstp, E);

    // ---- input projections ----
    init_proj4<<<gh4, 256, 0, stream>>>(x, pe_w, pe_b, (float4*)h, nh4);
    init_ep16<<<ge4, 256, 0, stream>>>(e_in, perm, ed_w, ed_b, (__half2*)ep, eh4);

    for (int l = 0; l < NLAYERS; l++) {
        node_gemm<<<(N + 63) / 64, 64, 0, stream>>>(h,
            Aw + l * 1024, Ab + l * 32,
            Bw + l * 1024, Bb + l * 32,
            Uw + l * 1024, Ub + l * 32,
            Vw + l * 1024, Vb + l * 32,
            Ah, Bh, hnew, Vh, N);
        if (l == 0)
            edge_en<0><<<GRID_STRIDE, 256, 0, stream>>>(ep, stats + 64, stats + 96,
                srcp, dstp, Ah, Bh, Cw + l * 1024, Cb + l * 32, enh, partial_e, E);
        else
            edge_en<1><<<GRID_STRIDE, 256, 0, stream>>>(ep, stats + 64, stats + 96,
                srcp, dstp, Ah, Bh, Cw + l * 1024, Cb + l * 32, enh, partial_e, E);
        stats_side<<<32, 256, 0, stream>>>(partial_e, GRID_STRIDE, (double)E,
            bn_e_g + l * 32, bn_e_b + l * 32, stats + 64, stats + 96);
        node_agg<<<GRID_STRIDE, 256, 0, stream>>>(enh, srcp, offsets, counts,
            Vh, hnew, partial_h, N);
        stats_side<<<32, 256, 0, stream>>>(partial_h, GRID_STRIDE, (double)N,
            bn_h_g + l * 32, bn_h_b + l * 32, stats + 0, stats + 32);
        if (l < NLAYERS - 1)
            apply4<<<gh4, 256, 0, stream>>>((const float4*)hnew, stats + 0, stats + 32,
                                            (float4*)h, nh4);
        else
            apply4_h16<<<gh4, 256, 0, stream>>>((const float4*)hnew, stats + 0, stats + 32,
                                                (const float4*)h, (__half2*)Ah, nh4);
    }

    predictor<<<GRID_STRIDE, 256, 0, stream>>>((const __half*)Ah, (const __half*)ep,
                                               (const __half*)enh, stats + 64, stats + 96,
                                               srcp, dstp, perm, W1w, W1b, W2w, W2b,
                                               (float*)d_out, E);
}